// Round 1
// baseline (468.035 us; speedup 1.0000x reference)
//
#include <hip/hip_runtime.h>
#include <hip/hip_bf16.h>

typedef unsigned short u16;
typedef __attribute__((ext_vector_type(4))) float f32x4;
typedef __attribute__((ext_vector_type(8))) short bf16x8;
typedef __attribute__((ext_vector_type(4))) short bf16x4;
typedef __attribute__((ext_vector_type(4))) unsigned short u16x4;

static __device__ __forceinline__ u16 f2bf(float f) {
    union { float f; unsigned u; } v; v.f = f;
    unsigned r = v.u + 0x7fffu + ((v.u >> 16) & 1u);
    return (u16)(r >> 16);
}

// ---------------- weight transpose + cast: out[n*K+k] = (bf16) W[k*N+n] ---------------
__global__ __launch_bounds__(256) void transpose_cast_b(
    const float* __restrict__ W, u16* __restrict__ out,
    int K, int N, long in_bs, long out_bs)
{
    __shared__ float tile[32][33];
    const float* Wb = W + (size_t)blockIdx.z * in_bs;
    u16* ob = out + (size_t)blockIdx.z * out_bs;
    int nt = blockIdx.x * 32, kt = blockIdx.y * 32;
    int tx = threadIdx.x & 31, ty = threadIdx.x >> 5;
    #pragma unroll
    for (int i = ty; i < 32; i += 8)
        tile[i][tx] = Wb[(size_t)(kt + i) * N + nt + tx];
    __syncthreads();
    #pragma unroll
    for (int i = ty; i < 32; i += 8)
        ob[(size_t)(nt + i) * K + kt + tx] = f2bf(tile[tx][i]);
}

// ---------------- layernorm: fp32 in -> bf16 out (D = 1024) ---------------
__global__ __launch_bounds__(256) void ln_kernel(
    const float* __restrict__ x, const float* __restrict__ g,
    const float* __restrict__ be, u16* __restrict__ out)
{
    int row = blockIdx.x;
    int t = threadIdx.x;
    const float4* xr = (const float4*)(x + (size_t)row * 1024);
    float4 v = xr[t];
    float s = v.x + v.y + v.z + v.w;
    float sq = v.x * v.x + v.y * v.y + v.z * v.z + v.w * v.w;
    #pragma unroll
    for (int o = 1; o < 64; o <<= 1) {
        s  += __shfl_xor(s, o);
        sq += __shfl_xor(sq, o);
    }
    __shared__ float ps[4], pq[4];
    if ((t & 63) == 0) { ps[t >> 6] = s; pq[t >> 6] = sq; }
    __syncthreads();
    float S = ps[0] + ps[1] + ps[2] + ps[3];
    float Q = pq[0] + pq[1] + pq[2] + pq[3];
    float mu = S * (1.0f / 1024.0f);
    float var = Q * (1.0f / 1024.0f) - mu * mu;
    float rs = rsqrtf(var + 1e-5f);
    int d = t * 4;
    const float4 g4  = ((const float4*)g)[t];
    const float4 be4 = ((const float4*)be)[t];
    u16x4 o4;
    o4[0] = f2bf((v.x - mu) * rs * g4.x + be4.x);
    o4[1] = f2bf((v.y - mu) * rs * g4.y + be4.y);
    o4[2] = f2bf((v.z - mu) * rs * g4.z + be4.z);
    o4[3] = f2bf((v.w - mu) * rs * g4.w + be4.w);
    *(u16x4*)(out + (size_t)row * 1024 + d) = o4;
}

// ---------------- GEMM: C[M,N] = A[M,K](bf16) * Bt[N,K](bf16)^T, fp32 accum ----------
// EPI 0: C -> bf16.   EPI 1: C + bias[n] + res[m,n] -> fp32.   EPI 2: gelu(C + bias[n]) -> bf16.
template<int EPI>
__global__ __launch_bounds__(256) void gemm_bt(
    const u16* __restrict__ A, const u16* __restrict__ Bt,
    int M, int N, int K,
    const float* __restrict__ bias, const float* __restrict__ res,
    void* __restrict__ Cout)
{
    __shared__ u16 As[128][40];
    __shared__ u16 Bs[128][40];
    const int tm = blockIdx.y * 128, tn = blockIdx.x * 128;
    const int t = threadIdx.x;
    const int lane = t & 63, wave = t >> 6;
    const int wr = wave >> 1, wc = wave & 1;
    const int lq = lane & 15, lg = lane >> 4;
    f32x4 acc[4][4] = {};
    const int sr = t >> 1, sc = (t & 1) * 16;
    const u16* ag = A  + (size_t)(tm + sr) * K + sc;
    const u16* bg = Bt + (size_t)(tn + sr) * K + sc;
    for (int k0 = 0; k0 < K; k0 += 32) {
        *(uint4*)&As[sr][sc]     = *(const uint4*)(ag + k0);
        *(uint4*)&As[sr][sc + 8] = *(const uint4*)(ag + k0 + 8);
        *(uint4*)&Bs[sr][sc]     = *(const uint4*)(bg + k0);
        *(uint4*)&Bs[sr][sc + 8] = *(const uint4*)(bg + k0 + 8);
        __syncthreads();
        bf16x8 af[4], bfr[4];
        #pragma unroll
        for (int m = 0; m < 4; ++m)
            af[m] = *(const bf16x8*)&As[wr * 64 + m * 16 + lq][lg * 8];
        #pragma unroll
        for (int n = 0; n < 4; ++n)
            bfr[n] = *(const bf16x8*)&Bs[wc * 64 + n * 16 + lq][lg * 8];
        #pragma unroll
        for (int m = 0; m < 4; ++m)
            #pragma unroll
            for (int n = 0; n < 4; ++n)
                acc[m][n] = __builtin_amdgcn_mfma_f32_16x16x32_bf16(af[m], bfr[n], acc[m][n], 0, 0, 0);
        __syncthreads();
    }
    #pragma unroll
    for (int m = 0; m < 4; ++m) {
        #pragma unroll
        for (int n = 0; n < 4; ++n) {
            #pragma unroll
            for (int r = 0; r < 4; ++r) {
                int row = tm + wr * 64 + m * 16 + lg * 4 + r;
                int col = tn + wc * 64 + n * 16 + lq;
                float v = acc[m][n][r];
                if (EPI == 0) {
                    ((u16*)Cout)[(size_t)row * N + col] = f2bf(v);
                } else if (EPI == 1) {
                    ((float*)Cout)[(size_t)row * N + col] = v + bias[col] + res[(size_t)row * N + col];
                } else {
                    float xx = v + bias[col];
                    float ge = 0.5f * xx * (1.0f + erff(xx * 0.70710678118654752f));
                    ((u16*)Cout)[(size_t)row * N + col] = f2bf(ge);
                }
            }
        }
    }
}

// ---------------- causal flash attention --------------------------------------------
// qkv: [B*P, 3072] bf16  (cols 0..1023 q, 1024..2047 k, 2048..3071 v; head h at h*64)
// o:   [B*P, 1024] bf16  (heads concatenated)
__global__ __launch_bounds__(256) void attn_kernel(
    const u16* __restrict__ qkv, u16* __restrict__ o)
{
    const int P = 2048;
    int blk = blockIdx.x;
    int qt = blk & 31;            // P/64 tiles
    int bh = blk >> 5;
    int h = bh & 15, b = bh >> 4;
    int wave = threadIdx.x >> 6, lane = threadIdx.x & 63;
    int lq = lane & 15, lg = lane >> 4;
    int q0 = qt * 64 + wave * 16;
    const size_t RS = 3072;
    const u16* qptr = qkv + (size_t)(b * P + q0 + lq) * RS + h * 64 + lg * 8;
    bf16x8 qf0 = *(const bf16x8*)qptr;
    bf16x8 qf1 = *(const bf16x8*)(qptr + 32);
    float m_run = -1e30f, l_run = 0.0f;
    f32x4 accO[4] = {};
    for (int kv0 = 0; kv0 <= q0; kv0 += 16) {
        const u16* kptr = qkv + (size_t)(b * P + kv0 + lq) * RS + 1024 + h * 64 + lg * 8;
        bf16x8 kf0 = *(const bf16x8*)kptr;
        bf16x8 kf1 = *(const bf16x8*)(kptr + 32);
        f32x4 z = {0.0f, 0.0f, 0.0f, 0.0f};
        f32x4 st = __builtin_amdgcn_mfma_f32_16x16x32_bf16(kf0, qf0, z, 0, 0, 0);
        st = __builtin_amdgcn_mfma_f32_16x16x32_bf16(kf1, qf1, st, 0, 0, 0);
        // st[kv = lg*4+r][q = lq]
        bool last = (kv0 == q0);
        float s[4];
        float rmax = -1e30f;
        #pragma unroll
        for (int r = 0; r < 4; ++r) {
            float v = st[r] * 0.03125f;           // * D^-0.5
            if (last && (lg * 4 + r > lq)) v = -1e30f;
            s[r] = v;
            rmax = fmaxf(rmax, v);
        }
        rmax = fmaxf(rmax, __shfl_xor(rmax, 16));
        rmax = fmaxf(rmax, __shfl_xor(rmax, 32));
        float m_new = fmaxf(m_run, rmax);
        float alpha = __expf(m_run - m_new);
        float p[4], psum = 0.0f;
        #pragma unroll
        for (int r = 0; r < 4; ++r) { p[r] = __expf(s[r] - m_new); psum += p[r]; }
        psum += __shfl_xor(psum, 16);
        psum += __shfl_xor(psum, 32);
        l_run = l_run * alpha + psum;
        m_run = m_new;
        // P fragment is already in A-operand layout of 16x16x16: A[q=lq][kv=lg*4+j]
        bf16x4 pf;
        pf[0] = (short)f2bf(p[0]); pf[1] = (short)f2bf(p[1]);
        pf[2] = (short)f2bf(p[2]); pf[3] = (short)f2bf(p[3]);
        // rescale O accumulator rows by alpha(row)
        #pragma unroll
        for (int r = 0; r < 4; ++r) {
            float a_r = __shfl(alpha, lg * 4 + r);
            accO[0][r] *= a_r; accO[1][r] *= a_r;
            accO[2][r] *= a_r; accO[3][r] *= a_r;
        }
        const u16* vbase = qkv + (size_t)(b * P + kv0 + lg * 4) * RS + 2048 + h * 64 + lq;
        #pragma unroll
        for (int c = 0; c < 4; ++c) {
            bf16x4 vf;
            #pragma unroll
            for (int j = 0; j < 4; ++j)
                vf[j] = (short)vbase[(size_t)j * RS + c * 16];
            accO[c] = __builtin_amdgcn_mfma_f32_16x16x16bf16_1k(pf, vf, accO[c], 0, 0, 0);
        }
    }
    #pragma unroll
    for (int r = 0; r < 4; ++r) {
        float l_r = __shfl(l_run, lg * 4 + r);
        float inv = 1.0f / l_r;
        size_t orow = (size_t)(b * P + q0 + lg * 4 + r) * 1024 + h * 64;
        #pragma unroll
        for (int c = 0; c < 4; ++c)
            o[orow + c * 16 + lq] = f2bf(accO[c][r] * inv);
    }
}

extern "C" void kernel_launch(void* const* d_in, const int* in_sizes, int n_in,
                              void* d_out, int out_size, void* d_ws, size_t ws_size,
                              hipStream_t stream)
{
    const float* x   = (const float*)d_in[0];
    const float* Wq  = (const float*)d_in[1];
    const float* Wk  = (const float*)d_in[2];
    const float* Wv  = (const float*)d_in[3];
    const float* Wp  = (const float*)d_in[4];
    const float* bp  = (const float*)d_in[5];
    const float* W1  = (const float*)d_in[6];
    const float* b1  = (const float*)d_in[7];
    const float* W2  = (const float*)d_in[8];
    const float* b2  = (const float*)d_in[9];
    const float* g1  = (const float*)d_in[10];
    const float* be1 = (const float*)d_in[11];
    const float* g2  = (const float*)d_in[12];
    const float* be2 = (const float*)d_in[13];

    char* ws = (char*)d_ws;
    u16*  h     = (u16*)(ws + 0);           // 8.39 MB   (later reused by m)
    u16*  qkv   = (u16*)(ws + 8388608);     // 25.17 MB  (later reused by m)
    u16*  o     = (u16*)(ws + 33554432);    // 8.39 MB   (later reused by h2)
    float* x1   = (float*)(ws + 41943040);  // 16.78 MB
    u16*  wqkvT = (u16*)(ws + 58720256);    // 6.29 MB
    u16*  wpT   = (u16*)(ws + 65011712);    // 2.10 MB
    u16*  w1T   = (u16*)(ws + 67108864);    // 8.39 MB
    u16*  w2T   = (u16*)(ws + 75497472);    // 8.39 MB  -> total 80 MB
    u16*  m     = (u16*)(ws + 0);           // 33.55 MB aliases h+qkv (dead by then)
    u16*  h2    = o;                        // aliases o (dead by then)
    float* out  = (float*)d_out;

    // Weight repacks (bf16, B^T layout). Wq/Wk/Wv: per-head [1024][64] -> [64][1024].
    transpose_cast_b<<<dim3(2, 32, 16), 256, 0, stream>>>(Wq, wqkvT,           1024, 64, 65536, 65536);
    transpose_cast_b<<<dim3(2, 32, 16), 256, 0, stream>>>(Wk, wqkvT + 1048576, 1024, 64, 65536, 65536);
    transpose_cast_b<<<dim3(2, 32, 16), 256, 0, stream>>>(Wv, wqkvT + 2097152, 1024, 64, 65536, 65536);
    transpose_cast_b<<<dim3(32, 32, 1), 256, 0, stream>>>(Wp, wpT, 1024, 1024, 0, 0);
    transpose_cast_b<<<dim3(128, 32, 1), 256, 0, stream>>>(W1, w1T, 1024, 4096, 0, 0);
    transpose_cast_b<<<dim3(32, 128, 1), 256, 0, stream>>>(W2, w2T, 4096, 1024, 0, 0);

    ln_kernel<<<4096, 256, 0, stream>>>(x, g1, be1, h);
    gemm_bt<0><<<dim3(24, 32), 256, 0, stream>>>(h, wqkvT, 4096, 3072, 1024, nullptr, nullptr, qkv);
    attn_kernel<<<1024, 256, 0, stream>>>(qkv, o);
    gemm_bt<1><<<dim3(8, 32), 256, 0, stream>>>(o, wpT, 4096, 1024, 1024, bp, x, x1);
    ln_kernel<<<4096, 256, 0, stream>>>(x1, g2, be2, h2);
    gemm_bt<2><<<dim3(32, 32), 256, 0, stream>>>(h2, w1T, 4096, 4096, 1024, b1, nullptr, m);
    gemm_bt<1><<<dim3(8, 32), 256, 0, stream>>>(m, w2T, 4096, 1024, 4096, b2, x1, out);
}